// Round 1
// baseline (70.242 us; speedup 1.0000x reference)
//
#include <hip/hip_runtime.h>

#define POOL 7
#define NUM_ROIS 512
#define H_IMG 128
#define W_IMG 128
#define C_IMG 1024

__global__ __launch_bounds__(256) void roi_pool_bilinear_kernel(
    const float* __restrict__ img,   // (H, W, C)
    const int*   __restrict__ rois,  // (R, 4) as (x, y, w, h)
    float*       __restrict__ out)   // (R, P, P, C)
{
    const int cell = blockIdx.x;          // r*49 + py*7 + px
    const int r    = cell / 49;
    const int rem  = cell - r * 49;
    const int py   = rem / 7;
    const int px   = rem - py * 7;

    const int4 roi = ((const int4*)rois)[r];
    const int x = roi.x, y = roi.y, w = roi.z, h = roi.w;
    const float hf = (float)h, wf = (float)w;

    // Match reference fp32 math exactly: ys = clip((p+0.5)*hf/7 - 0.5, 0, hf-1)
    float ysf = ((float)py + 0.5f) * hf / 7.0f - 0.5f;
    ysf = fminf(fmaxf(ysf, 0.0f), hf - 1.0f);
    float xsf = ((float)px + 0.5f) * wf / 7.0f - 0.5f;
    xsf = fminf(fmaxf(xsf, 0.0f), wf - 1.0f);

    const int y0 = (int)floorf(ysf);
    const int x0 = (int)floorf(xsf);
    const int y1 = min(y0 + 1, h - 1);
    const int x1 = min(x0 + 1, w - 1);
    const float fy = ysf - (float)y0;
    const float fx = xsf - (float)x0;

    const int ay0 = y + y0, ay1 = y + y1;
    const int ax0 = x + x0, ax1 = x + x1;

    const float4* __restrict__ p00 =
        (const float4*)(img + ((size_t)ay0 * W_IMG + ax0) * C_IMG);
    const float4* __restrict__ p01 =
        (const float4*)(img + ((size_t)ay0 * W_IMG + ax1) * C_IMG);
    const float4* __restrict__ p10 =
        (const float4*)(img + ((size_t)ay1 * W_IMG + ax0) * C_IMG);
    const float4* __restrict__ p11 =
        (const float4*)(img + ((size_t)ay1 * W_IMG + ax1) * C_IMG);
    float4* __restrict__ po = (float4*)(out + (size_t)cell * C_IMG);

    const int t = threadIdx.x;   // 0..255 ; C/4 == 256 exactly

    const float4 a = p00[t];
    const float4 b = p01[t];
    const float4 c = p10[t];
    const float4 d = p11[t];

    const float gx = 1.0f - fx;
    const float gy = 1.0f - fy;

    float4 o;
    // top = a*(1-fx) + b*fx ; bot = c*(1-fx) + d*fx ; out = top*(1-fy) + bot*fy
    {
        float tx = a.x * gx + b.x * fx;
        float bx = c.x * gx + d.x * fx;
        o.x = tx * gy + bx * fy;
        float ty = a.y * gx + b.y * fx;
        float by = c.y * gx + d.y * fx;
        o.y = ty * gy + by * fy;
        float tz = a.z * gx + b.z * fx;
        float bz = c.z * gx + d.z * fx;
        o.z = tz * gy + bz * fy;
        float tw = a.w * gx + b.w * fx;
        float bw = c.w * gx + d.w * fx;
        o.w = tw * gy + bw * fy;
    }
    po[t] = o;
}

extern "C" void kernel_launch(void* const* d_in, const int* in_sizes, int n_in,
                              void* d_out, int out_size, void* d_ws, size_t ws_size,
                              hipStream_t stream) {
    const float* img  = (const float*)d_in[0];   // (1,128,128,1024) fp32
    const int*   rois = (const int*)d_in[1];     // (1,512,4) int32
    float*       out  = (float*)d_out;           // (1,512,7,7,1024) fp32

    const int cells = NUM_ROIS * POOL * POOL;    // 25088
    roi_pool_bilinear_kernel<<<cells, 256, 0, stream>>>(img, rois, out);
}

// Round 3
// 61.933 us; speedup vs baseline: 1.1342x; 1.1342x over previous
//
#include <hip/hip_runtime.h>

#define POOL 7
#define NUM_ROIS 512
#define H_IMG 128
#define W_IMG 128
#define C_IMG 1024
#define NBLK (NUM_ROIS * POOL)   // 3584, one block per (roi, py) row

typedef float f32x4 __attribute__((ext_vector_type(4)));

__global__ __launch_bounds__(256) void roi_pool_row_kernel(
    const float* __restrict__ img,   // (H, W, C)
    const int*   __restrict__ rois,  // (R, 4) as (x, y, w, h)
    float*       __restrict__ out)   // (R, P, P, C)
{
    // XCD-aware swizzle: 3584 % 8 == 0, so simple bijective remap.
    const int bid = blockIdx.x;
    const int swz = (bid & 7) * (NBLK / 8) + (bid >> 3);
    const int r   = swz / POOL;
    const int py  = swz - r * POOL;

    const int4 roi = ((const int4*)rois)[r];
    const int x = roi.x, y = roi.y, w = roi.z, h = roi.w;
    const float hf = (float)h, wf = (float)w;

    // y interpolation (same fp32 expression order as reference)
    float ysf = ((float)py + 0.5f) * hf / 7.0f - 0.5f;
    ysf = fminf(fmaxf(ysf, 0.0f), hf - 1.0f);
    const int   y0 = (int)floorf(ysf);
    const int   y1 = min(y0 + 1, h - 1);
    const float fy = ysf - (float)y0;
    const float gy = 1.0f - fy;

    const f32x4* __restrict__ row0 =
        (const f32x4*)(img + (size_t)(y + y0) * W_IMG * C_IMG);
    const f32x4* __restrict__ row1 =
        (const f32x4*)(img + (size_t)(y + y1) * W_IMG * C_IMG);

    // x interpolation for all 7 px
    int   ax0[POOL], ax1[POOL];
    float fx[POOL];
    #pragma unroll
    for (int px = 0; px < POOL; ++px) {
        float xsf = ((float)px + 0.5f) * wf / 7.0f - 0.5f;
        xsf = fminf(fmaxf(xsf, 0.0f), wf - 1.0f);
        const int x0 = (int)floorf(xsf);
        const int x1 = min(x0 + 1, w - 1);
        fx[px]  = xsf - (float)x0;
        ax0[px] = x + x0;
        ax1[px] = x + x1;
    }

    const int t = threadIdx.x;   // 0..255 ; C/4 == 256 exactly

    // Batch 1: top row — 14 independent loads in flight
    f32x4 A[POOL], B[POOL];
    #pragma unroll
    for (int px = 0; px < POOL; ++px) {
        A[px] = row0[(ax0[px] << 8) + t];
        B[px] = row0[(ax1[px] << 8) + t];
    }
    f32x4 T[POOL];
    #pragma unroll
    for (int px = 0; px < POOL; ++px) {
        const float f = fx[px], g = 1.0f - f;
        T[px] = A[px] * g + B[px] * f;
    }

    // Batch 2: bottom row — 14 more independent loads
    f32x4 C_[POOL], D[POOL];
    #pragma unroll
    for (int px = 0; px < POOL; ++px) {
        C_[px] = row1[(ax0[px] << 8) + t];
        D[px]  = row1[(ax1[px] << 8) + t];
    }

    f32x4* __restrict__ po =
        (f32x4*)(out + ((size_t)(r * 49 + py * 7)) * C_IMG);

    #pragma unroll
    for (int px = 0; px < POOL; ++px) {
        const float f = fx[px], g = 1.0f - f;
        f32x4 bot = C_[px] * g + D[px] * f;
        f32x4 o   = T[px] * gy + bot * fy;
        // Output is write-once, never re-read: bypass cache allocation.
        __builtin_nontemporal_store(o, &po[(px << 8) + t]);
    }
}

extern "C" void kernel_launch(void* const* d_in, const int* in_sizes, int n_in,
                              void* d_out, int out_size, void* d_ws, size_t ws_size,
                              hipStream_t stream) {
    const float* img  = (const float*)d_in[0];   // (1,128,128,1024) fp32
    const int*   rois = (const int*)d_in[1];     // (1,512,4) int32
    float*       out  = (float*)d_out;           // (1,512,7,7,1024) fp32

    roi_pool_row_kernel<<<NBLK, 256, 0, stream>>>(img, rois, out);
}

// Round 4
// 38.406 us; speedup vs baseline: 1.8289x; 1.6126x over previous
//
#include <hip/hip_runtime.h>

#define POOL 7
#define NUM_ROIS 512
#define H_IMG 128
#define W_IMG 128
#define C_IMG 1024
#define NITEMS (NUM_ROIS * POOL)   // 3584 work items = (roi, py) rows

typedef float f32x4 __attribute__((ext_vector_type(4)));

// ---------------------------------------------------------------------------
// Pre-pass: counting-sort the 3584 (roi,py) work items by source image row
// ay0 = y + y0, so that consecutive blocks (=> same XCD under the swizzle)
// read the same image rows while they are still resident in that XCD's L2.
// Single block; rewrites perm[0..NITEMS) entirely every call (no stale state).
// Within-bin order depends on atomic timing, but every work item writes a
// disjoint output slice, so the final output is order-independent.
// ---------------------------------------------------------------------------
__device__ __forceinline__ int item_key(const int4 roi, int py) {
    const float hf = (float)roi.w;                       // h
    float ysf = ((float)py + 0.5f) * hf / 7.0f - 0.5f;
    ysf = fminf(fmaxf(ysf, 0.0f), hf - 1.0f);
    return roi.y + (int)floorf(ysf);                     // ay0 in [0,127]
}

__global__ __launch_bounds__(1024) void build_perm_kernel(
    const int* __restrict__ rois, int* __restrict__ perm)
{
    __shared__ int hist[128];
    __shared__ int offs[128];
    const int tid = threadIdx.x;
    if (tid < 128) hist[tid] = 0;
    __syncthreads();

    for (int i = tid; i < NITEMS; i += 1024) {
        const int r = i / POOL, py = i - r * POOL;
        const int4 roi = ((const int4*)rois)[r];
        atomicAdd(&hist[item_key(roi, py)], 1);
    }
    __syncthreads();

    if (tid == 0) {                       // 128-bin exclusive scan, serial
        int acc = 0;
        for (int b = 0; b < 128; ++b) { offs[b] = acc; acc += hist[b]; }
    }
    __syncthreads();
    if (tid < 128) hist[tid] = offs[tid]; // reuse hist as scatter cursor
    __syncthreads();

    for (int i = tid; i < NITEMS; i += 1024) {
        const int r = i / POOL, py = i - r * POOL;
        const int4 roi = ((const int4*)rois)[r];
        const int pos = atomicAdd(&hist[item_key(roi, py)], 1);
        perm[pos] = i;
    }
}

// ---------------------------------------------------------------------------
// Main kernel: one 256-thread block per (roi, py) output row, work order
// taken from perm so that each XCD streams through a contiguous y-slice.
// ---------------------------------------------------------------------------
__global__ __launch_bounds__(256) void roi_pool_row_kernel(
    const float* __restrict__ img,   // (H, W, C)
    const int*   __restrict__ rois,  // (R, 4) as (x, y, w, h)
    const int*   __restrict__ perm,  // (NITEMS) sorted work ids
    float*       __restrict__ out)   // (R, P, P, C)
{
    // XCD-aware swizzle: round-robin dispatch => bid&7 is the XCD; give each
    // XCD a contiguous chunk of the row-sorted work list.
    const int bid  = blockIdx.x;
    const int swz  = (bid & 7) * (NITEMS / 8) + (bid >> 3);
    const int item = perm[swz];
    const int r    = item / POOL;
    const int py   = item - r * POOL;

    const int4 roi = ((const int4*)rois)[r];
    const int x = roi.x, y = roi.y, w = roi.z, h = roi.w;
    const float hf = (float)h, wf = (float)w;

    // y interpolation (same fp32 expression order as reference)
    float ysf = ((float)py + 0.5f) * hf / 7.0f - 0.5f;
    ysf = fminf(fmaxf(ysf, 0.0f), hf - 1.0f);
    const int   y0 = (int)floorf(ysf);
    const int   y1 = min(y0 + 1, h - 1);
    const float fy = ysf - (float)y0;
    const float gy = 1.0f - fy;

    const f32x4* __restrict__ row0 =
        (const f32x4*)(img + (size_t)(y + y0) * W_IMG * C_IMG);
    const f32x4* __restrict__ row1 =
        (const f32x4*)(img + (size_t)(y + y1) * W_IMG * C_IMG);

    // x interpolation for all 7 px
    int   ax0[POOL], ax1[POOL];
    float fx[POOL];
    #pragma unroll
    for (int px = 0; px < POOL; ++px) {
        float xsf = ((float)px + 0.5f) * wf / 7.0f - 0.5f;
        xsf = fminf(fmaxf(xsf, 0.0f), wf - 1.0f);
        const int x0 = (int)floorf(xsf);
        const int x1 = min(x0 + 1, w - 1);
        fx[px]  = xsf - (float)x0;
        ax0[px] = x + x0;
        ax1[px] = x + x1;
    }

    const int t = threadIdx.x;   // 0..255 ; C/4 == 256 exactly

    // Batch 1: top row — 14 independent loads in flight
    f32x4 A[POOL], B[POOL];
    #pragma unroll
    for (int px = 0; px < POOL; ++px) {
        A[px] = row0[(ax0[px] << 8) + t];
        B[px] = row0[(ax1[px] << 8) + t];
    }
    f32x4 T[POOL];
    #pragma unroll
    for (int px = 0; px < POOL; ++px) {
        const float f = fx[px], g = 1.0f - f;
        T[px] = A[px] * g + B[px] * f;
    }

    // Batch 2: bottom row — 14 more independent loads
    f32x4 C_[POOL], D[POOL];
    #pragma unroll
    for (int px = 0; px < POOL; ++px) {
        C_[px] = row1[(ax0[px] << 8) + t];
        D[px]  = row1[(ax1[px] << 8) + t];
    }

    f32x4* __restrict__ po =
        (f32x4*)(out + ((size_t)(r * 49 + py * 7)) * C_IMG);

    #pragma unroll
    for (int px = 0; px < POOL; ++px) {
        const float f = fx[px], g = 1.0f - f;
        f32x4 bot = C_[px] * g + D[px] * f;
        f32x4 o   = T[px] * gy + bot * fy;
        // Output is write-once, never re-read: bypass cache allocation.
        __builtin_nontemporal_store(o, &po[(px << 8) + t]);
    }
}

extern "C" void kernel_launch(void* const* d_in, const int* in_sizes, int n_in,
                              void* d_out, int out_size, void* d_ws, size_t ws_size,
                              hipStream_t stream) {
    const float* img  = (const float*)d_in[0];   // (1,128,128,1024) fp32
    const int*   rois = (const int*)d_in[1];     // (1,512,4) int32
    float*       out  = (float*)d_out;           // (1,512,7,7,1024) fp32
    int*         perm = (int*)d_ws;              // NITEMS ints of scratch

    build_perm_kernel<<<1, 1024, 0, stream>>>(rois, perm);
    roi_pool_row_kernel<<<NITEMS, 256, 0, stream>>>(img, rois, perm, out);
}

// Round 5
// 37.778 us; speedup vs baseline: 1.8593x; 1.0166x over previous
//
#include <hip/hip_runtime.h>

#define POOL 7
#define NUM_ROIS 512
#define H_IMG 128
#define W_IMG 128
#define C_IMG 1024
#define NITEMS (NUM_ROIS * POOL)   // 3584 work items = (roi, py) rows

typedef float f32x4 __attribute__((ext_vector_type(4)));

// ---------------------------------------------------------------------------
// Pre-pass: counting-sort the 3584 (roi,py) work items by source image row
// ay0 = y + y0. Fully parallel scan (Hillis-Steele over 128 bins) — the
// previous serial thread-0 scan cost ~4-5 us of dependent LDS latency.
// Rewrites perm[] entirely every call; within-bin order is atomic-timing
// dependent but harmless (each item writes a disjoint output slice).
// ---------------------------------------------------------------------------
__device__ __forceinline__ int item_key(const int4 roi, int py) {
    const float hf = (float)roi.w;                       // h
    float ysf = ((float)py + 0.5f) * hf / 7.0f - 0.5f;
    ysf = fminf(fmaxf(ysf, 0.0f), hf - 1.0f);
    return roi.y + (int)floorf(ysf);                     // ay0 in [0,127]
}

__global__ __launch_bounds__(1024) void build_perm_kernel(
    const int* __restrict__ rois, int* __restrict__ perm)
{
    __shared__ int hist[128];
    __shared__ int scan[128];
    const int tid = threadIdx.x;
    if (tid < 128) hist[tid] = 0;
    __syncthreads();

    for (int i = tid; i < NITEMS; i += 1024) {
        const int r = i / POOL, py = i - r * POOL;
        const int4 roi = ((const int4*)rois)[r];
        atomicAdd(&hist[item_key(roi, py)], 1);
    }
    __syncthreads();

    // Inclusive Hillis-Steele scan over 128 bins, 128 threads, 7 steps.
    if (tid < 128) scan[tid] = hist[tid];
    __syncthreads();
    #pragma unroll
    for (int off = 1; off < 128; off <<= 1) {
        int v = 0;
        if (tid < 128 && tid >= off) v = scan[tid - off];
        __syncthreads();
        if (tid < 128) scan[tid] += v;
        __syncthreads();
    }
    // Exclusive offset as scatter cursor (reuse hist).
    if (tid < 128) hist[tid] = scan[tid] - hist[tid];
    __syncthreads();

    for (int i = tid; i < NITEMS; i += 1024) {
        const int r = i / POOL, py = i - r * POOL;
        const int4 roi = ((const int4*)rois)[r];
        const int pos = atomicAdd(&hist[item_key(roi, py)], 1);
        perm[pos] = i;
    }
}

// ---------------------------------------------------------------------------
// Main kernel: one 256-thread block per (roi, py) output row, work order
// from perm so each XCD streams a contiguous y-slice. All 28 gathers are
// issued before any arithmetic for maximum memory-level parallelism.
// ---------------------------------------------------------------------------
__global__ __launch_bounds__(256) void roi_pool_row_kernel(
    const float* __restrict__ img,   // (H, W, C)
    const int*   __restrict__ rois,  // (R, 4) as (x, y, w, h)
    const int*   __restrict__ perm,  // (NITEMS) sorted work ids
    float*       __restrict__ out)   // (R, P, P, C)
{
    const int bid  = blockIdx.x;
    const int swz  = (bid & 7) * (NITEMS / 8) + (bid >> 3);
    const int item = perm[swz];
    const int r    = item / POOL;
    const int py   = item - r * POOL;

    const int4 roi = ((const int4*)rois)[r];
    const int x = roi.x, y = roi.y, w = roi.z, h = roi.w;
    const float hf = (float)h, wf = (float)w;

    // y interpolation (same fp32 expression order as reference)
    float ysf = ((float)py + 0.5f) * hf / 7.0f - 0.5f;
    ysf = fminf(fmaxf(ysf, 0.0f), hf - 1.0f);
    const int   y0 = (int)floorf(ysf);
    const int   y1 = min(y0 + 1, h - 1);
    const float fy = ysf - (float)y0;
    const float gy = 1.0f - fy;

    const f32x4* __restrict__ row0 =
        (const f32x4*)(img + (size_t)(y + y0) * W_IMG * C_IMG);
    const f32x4* __restrict__ row1 =
        (const f32x4*)(img + (size_t)(y + y1) * W_IMG * C_IMG);

    // x interpolation for all 7 px
    int   ax0[POOL], ax1[POOL];
    float fx[POOL];
    #pragma unroll
    for (int px = 0; px < POOL; ++px) {
        float xsf = ((float)px + 0.5f) * wf / 7.0f - 0.5f;
        xsf = fminf(fmaxf(xsf, 0.0f), wf - 1.0f);
        const int x0 = (int)floorf(xsf);
        const int x1 = min(x0 + 1, w - 1);
        fx[px]  = xsf - (float)x0;
        ax0[px] = x + x0;
        ax1[px] = x + x1;
    }

    const int t = threadIdx.x;   // 0..255 ; C/4 == 256 exactly

    // Issue ALL 28 independent loads before any blending.
    f32x4 A[POOL], B[POOL], C_[POOL], D[POOL];
    #pragma unroll
    for (int px = 0; px < POOL; ++px) {
        A[px]  = row0[(ax0[px] << 8) + t];
        B[px]  = row0[(ax1[px] << 8) + t];
    }
    #pragma unroll
    for (int px = 0; px < POOL; ++px) {
        C_[px] = row1[(ax0[px] << 8) + t];
        D[px]  = row1[(ax1[px] << 8) + t];
    }

    f32x4* __restrict__ po =
        (f32x4*)(out + ((size_t)(r * 49 + py * 7)) * C_IMG);

    #pragma unroll
    for (int px = 0; px < POOL; ++px) {
        const float f = fx[px], g = 1.0f - f;
        f32x4 top = A[px]  * g + B[px] * f;
        f32x4 bot = C_[px] * g + D[px] * f;
        f32x4 o   = top * gy + bot * fy;
        // Output is write-once, never re-read: bypass cache allocation.
        __builtin_nontemporal_store(o, &po[(px << 8) + t]);
    }
}

extern "C" void kernel_launch(void* const* d_in, const int* in_sizes, int n_in,
                              void* d_out, int out_size, void* d_ws, size_t ws_size,
                              hipStream_t stream) {
    const float* img  = (const float*)d_in[0];   // (1,128,128,1024) fp32
    const int*   rois = (const int*)d_in[1];     // (1,512,4) int32
    float*       out  = (float*)d_out;           // (1,512,7,7,1024) fp32
    int*         perm = (int*)d_ws;              // NITEMS ints of scratch

    build_perm_kernel<<<1, 1024, 0, stream>>>(rois, perm);
    roi_pool_row_kernel<<<NITEMS, 256, 0, stream>>>(img, rois, perm, out);
}